// Round 13
// baseline (192.455 us; speedup 1.0000x reference)
//
#include <hip/hip_runtime.h>
#include <hip/hip_bf16.h>
#include <cmath>

#define NSP 119
#define UNITS 512
#define NFEAT 360
#define KP1 384          // NFEAT padded to multiple of 32
#define CAP 128          // per-atom pair-segment capacity (mean ~21, >13 sigma)

typedef __attribute__((ext_vector_type(8))) short short8;
typedef __attribute__((ext_vector_type(4))) float floatx4;

#define AS1 __attribute__((address_space(1)))
#define AS3 __attribute__((address_space(3)))

// async global->LDS, 16B per lane; lds dest = wave-uniform base + lane*16
__device__ __forceinline__ void gload_lds16(const void* g, void* l) {
    __builtin_amdgcn_global_load_lds((AS1 void*)(size_t)g, (AS3 void*)l, 16, 0, 0);
}

// compile-time symmetric-index helpers (fold under full unroll)
__device__ __host__ constexpr int s2c(int i, int j) {
    return (i > j) ? i*(i+1)/2 + j : j*(j+1)/2 + i;
}
__device__ __host__ constexpr int s3c(int x, int y, int z) {
    int A = x > y ? x : y; A = A > z ? A : z;
    int C = x < y ? x : y; C = C < z ? C : z;
    int B = x + y + z - A - C;
    return A*(A+1)*(A+2)/6 + B*(B+1)/2 + C;
}

struct BasisConsts {
    float f0k;      // -betta * log2(e)
    float kg;       // 2*betta*delta*log2(e)
    float scale;    // rad_norm / sqrt(7)
    float c[6];     // exp(-betta*delta*(1 + delta*(2b+1)))
};

// ---------- phase 1 (fused): pair records + W transposes + out init ----------
__global__ __launch_bounds__(256) void pair_prep_kernel(
    const float* __restrict__ R, const int* __restrict__ Z,
    const int* __restrict__ nbr, const float* __restrict__ offsets,
    const float* __restrict__ emb, int* __restrict__ counts,
    float* __restrict__ tmpRec, int npairs, BasisConsts bc,
    const float* __restrict__ W1, const float* __restrict__ W2,
    __hip_bfloat16* __restrict__ W1t, __hip_bfloat16* __restrict__ W2t,
    float* __restrict__ outbuf, const float* __restrict__ b3,
    int pgrid, int natoms)
{
    int blk = blockIdx.x;
    if (blk >= pgrid) {
        int b = blk - pgrid;
        if (b < 448) {
            __shared__ float tile[32][33];
            const float* W; __hip_bfloat16* Wt; int K, Kp, ik, in;
            if (b < 192) { W = W1; Wt = W1t; K = NFEAT; Kp = KP1; ik = b % 12; in = b / 12; }
            else { int b2 = b - 192; W = W2; Wt = W2t; K = UNITS; Kp = UNITS; ik = b2 & 15; in = b2 >> 4; }
            int tx = threadIdx.x & 31, ty = threadIdx.x >> 5;
            int n = in * 32 + tx;                      // N = 512 for both matrices
            #pragma unroll
            for (int pp = 0; pp < 4; ++pp) {
                int kk = ty + pp * 8;
                int k = ik * 32 + kk;
                tile[kk][tx] = (k < K) ? W[(size_t)k * UNITS + n] : 0.f;
            }
            __syncthreads();
            #pragma unroll
            for (int pp = 0; pp < 4; ++pp) {
                int nn = ty + pp * 8;
                Wt[(size_t)(in * 32 + nn) * Kp + ik * 32 + tx] = __float2bfloat16(tile[tx][nn]);
            }
        } else {
            int idx = (b - 448) * 256 + threadIdx.x;
            if (idx < natoms)
                outbuf[idx] = (Z[idx] > 0) ? 0.1f * b3[0] : 0.f;
        }
        return;
    }

    int p = blk * 256 + threadIdx.x;
    if (p >= npairs) return;
    int i = nbr[p];
    int j = nbr[npairs + p];
    float dx = R[3*j]   - R[3*i]   + offsets[3*p];
    float dy = R[3*j+1] - R[3*i+1] + offsets[3*p+1];
    float dz = R[3*j+2] - R[3*i+2] + offsets[3*p+2];
    float dr2 = fmaf(dz, dz, fmaf(dy, dy, dx*dx));
    if (dr2 >= 36.0f) return;
    int pos = atomicAdd(&counts[i], 1);
    if (pos >= CAP) return;   // statistically impossible; memory-safety guard

    float dr  = sqrtf(dr2);
    float inv = 1.0f / (dr + 1e-5f);
    float d0  = dr - 0.5f;
    float basis[7];
    basis[0] = exp2f(bc.f0k * d0 * d0);
    float G  = exp2f(bc.kg * dr);
    float cur = basis[0];
    #pragma unroll
    for (int b = 0; b < 6; ++b) { cur *= G * bc.c[b]; basis[b+1] = cur; }
    float cut = 0.5f * (__cosf(dr * 0.52359877559829887f) + 1.0f);  // pi/R_MAX
    float s = bc.scale * cut;

    const float* e = emb + ((size_t)Z[j] * NSP + Z[i]) * 35;
    float ev[35];
    __builtin_memcpy(ev, e, 35 * sizeof(float));

    float rec[8];
    #pragma unroll
    for (int r = 0; r < 5; ++r) {
        float acc = 0.f;
        #pragma unroll
        for (int b = 0; b < 7; ++b) acc += ev[r*7+b] * basis[b];
        rec[r] = s * acc;
    }
    rec[5] = dx * inv; rec[6] = dy * inv; rec[7] = dz * inv;
    float4* out = (float4*)(tmpRec + ((size_t)i * CAP + pos) * 8);
    out[0] = make_float4(rec[0], rec[1], rec[2], rec[3]);
    out[1] = make_float4(rec[4], rec[5], rec[6], rec[7]);
}

// ---------- phase 2a: one wave per atom -> 100 compressed moments to global ----------
#define SREC 28
__global__ __launch_bounds__(256) void moment_kernel(
    const float* __restrict__ tmpRec, const int* __restrict__ counts,
    float* __restrict__ momG, int natoms)
{
    int wv = threadIdx.x >> 6, lane = threadIdx.x & 63;
    int a = blockIdx.x * 4 + wv;
    __shared__ float stage[4][64][SREC];

    int cnt = 0;
    if (a < natoms) cnt = min(counts[a], CAP);   // pad atoms: zeros

    int cr0, pk0;
    if (lane < 5)       { cr0 = lane;            pk0 = 0; }
    else if (lane < 20) { int c = lane - 5;      cr0 = c / 3;  pk0 = 1 + c % 3; }
    else if (lane < 50) { int c = lane - 20;     cr0 = c / 6;  pk0 = 4 + c % 6; }
    else                { int c = lane - 50;     cr0 = c / 10; pk0 = 10 + c % 10; }
    int cr1 = 0, pk1 = 0;
    if (lane < 36) { int c = 14 + lane; cr1 = c / 10; pk1 = 10 + c % 10; }

    float acc0 = 0.f, acc1 = 0.f;
    for (int base = 0; base < cnt; base += 64) {
        int m = min(64, cnt - base);
        if (lane < m) {
            const float4* pd = (const float4*)(tmpRec + ((size_t)a * CAP + base + lane) * 8);
            float4 u = pd[0], v = pd[1];
            float x = v.y, y = v.z, z = v.w;
            float s2_0 = x*x, s2_1 = y*x, s2_2 = y*y, s2_3 = z*x, s2_4 = z*y, s2_5 = z*z;
            float* st = stage[wv][lane];
            ((float4*)st)[0] = u;                                    // rad0..3
            ((float4*)st)[1] = make_float4(v.x, 1.0f, x, y);         // rad4, p0=1, p1, p2
            ((float4*)st)[2] = make_float4(z, s2_0, s2_1, s2_2);     // p3..p6
            ((float4*)st)[3] = make_float4(s2_3, s2_4, s2_5, s2_0*x);// p7..p9, p10=xxx
            ((float4*)st)[4] = make_float4(s2_0*y, s2_2*x, s2_2*y, s2_0*z); // p11..p14
            ((float4*)st)[5] = make_float4(s2_1*z, s2_2*z, s2_5*x, s2_5*y); // p15..p18
            ((float4*)st)[6] = make_float4(s2_5*z, 0.f, 0.f, 0.f);   // p19, pad
        }
        __builtin_amdgcn_wave_barrier();
        for (int q = 0; q < m; ++q) {
            const float* s = stage[wv][q];
            acc0 += s[cr0] * s[5 + pk0];
            acc1 += s[cr1] * s[5 + pk1];
        }
        __builtin_amdgcn_wave_barrier();
    }
    size_t base = (size_t)(a >> 6) * 6400 + (size_t)(a & 63);
    momG[base + (size_t)lane * 64] = acc0;
    if (lane < 36) momG[base + (size_t)(64 + lane) * 64] = acc1;
}

// ---------- phase 2b: lane = atom, wave = feature group; all indices constexpr ----------
#define LROW 390   // LDS row stride in bf16: 195 words, 195%32=3 -> conflict-free
__global__ __launch_bounds__(256) void feat_kernel(
    const float* __restrict__ momG, __hip_bfloat16* __restrict__ feats)
{
    constexpr int cT2I[15] = {0,1,1,2,2,2,3,3,3,3,4,4,4,4,4};
    constexpr int cT2J[15] = {0,0,1,0,1,2,0,1,2,3,0,1,2,3,4};
    constexpr int cT3A[35] = {0, 1,1,1, 2,2,2,2,2,2, 3,3,3,3,3,3,3,3,3,3, 4,4,4,4,4,4,4,4,4,4,4,4,4,4,4};
    constexpr int cT3B[35] = {0, 0,1,1, 0,1,1,2,2,2, 0,1,1,2,2,2,3,3,3,3, 0,1,1,2,2,2,3,3,3,3,4,4,4,4,4};
    constexpr int cT3C[35] = {0, 0,0,1, 0,0,1,0,1,2, 0,0,1,0,1,2,0,1,2,3, 0,0,1,0,1,2,0,1,2,3,0,1,2,3,4};
    constexpr float cW2[6]  = {1.f,2.f,1.f,2.f,2.f,1.f};
    constexpr float cW3[10] = {1.f,3.f,3.f,1.f,3.f,6.f,3.f,3.f,3.f,1.f};

    __shared__ __hip_bfloat16 ldsF[64][LROW];
    int wv = threadIdx.x >> 6, lane = threadIdx.x & 63;
    const float* mg = momG + (size_t)blockIdx.x * 6400 + lane;

    #define LDM(e) mg[(e) * 64]
    #define STF(f, v) ldsF[lane][(f)] = __float2bfloat16(v)

    if (wv == 0) {
        float m3[50], m2[30];
        #pragma unroll
        for (int e = 0; e < 50; ++e) m3[e] = LDM(50 + e);
        #pragma unroll
        for (int e = 0; e < 30; ++e) m2[e] = LDM(20 + e);
        #pragma unroll
        for (int p = 0; p < 10; ++p) {
            int r = cT2I[p], s = cT2J[p];
            float B2v[9];
            #pragma unroll
            for (int z = 0; z < 3; ++z)
                #pragma unroll
                for (int w = 0; w < 3; ++w) {
                    float acc = 0.f;
                    #pragma unroll
                    for (int x = 0; x < 3; ++x)
                        #pragma unroll
                        for (int y = 0; y < 3; ++y)
                            acc += m3[r*10 + s3c(x,y,z)] * m3[s*10 + s3c(x,y,w)];
                    B2v[z*3+w] = acc;
                }
            #pragma unroll
            for (int t = 0; t < 5; ++t) {
                float acc = 0.f;
                #pragma unroll
                for (int z = 0; z < 3; ++z)
                    #pragma unroll
                    for (int w = 0; w < 3; ++w)
                        acc += B2v[z*3+w] * m2[t*6 + s2c(z,w)];
                STF(160 + p*5 + t, acc);
            }
        }
    } else if (wv == 1) {
        float m0[5], m1[15], m2[30];
        #pragma unroll
        for (int e = 0; e < 5; ++e)  m0[e] = LDM(e);
        #pragma unroll
        for (int e = 0; e < 15; ++e) m1[e] = LDM(5 + e);
        #pragma unroll
        for (int e = 0; e < 30; ++e) m2[e] = LDM(20 + e);
        #pragma unroll
        for (int r = 0; r < 5; ++r) STF(r, m0[r]);
        #pragma unroll
        for (int p = 0; p < 15; ++p) {
            int r = cT2I[p], s = cT2J[p];
            float v1 = m1[r*3]*m1[s*3] + m1[r*3+1]*m1[s*3+1] + m1[r*3+2]*m1[s*3+2];
            STF(5 + p, v1);
            float v2 = 0.f;
            #pragma unroll
            for (int k = 0; k < 6; ++k) v2 += cW2[k] * m2[r*6+k] * m2[s*6+k];
            STF(20 + p, v2);
        }
        #pragma unroll
        for (int q = 0; q < 35; ++q) {
            int r = cT3A[q], s = cT3B[q], t = cT3C[q];
            float v = 0.f;
            #pragma unroll
            for (int x = 0; x < 3; ++x)
                #pragma unroll
                for (int y = 0; y < 3; ++y) {
                    float d = 0.f;
                    #pragma unroll
                    for (int z = 0; z < 3; ++z)
                        d += m2[s*6 + s2c(x,z)] * m2[t*6 + s2c(y,z)];
                    v += m2[r*6 + s2c(x,y)] * d;
                }
            STF(50 + q, v);
        }
        #pragma unroll
        for (int f = NFEAT; f < KP1; ++f) STF(f, 0.f);
    } else if (wv == 2) {
        float m1[15], m2[30], m3[50];
        #pragma unroll
        for (int e = 0; e < 15; ++e) m1[e] = LDM(5 + e);
        #pragma unroll
        for (int e = 0; e < 30; ++e) m2[e] = LDM(20 + e);
        #pragma unroll
        for (int e = 0; e < 50; ++e) m3[e] = LDM(50 + e);
        #pragma unroll
        for (int p = 10; p < 15; ++p) {
            int r = cT2I[p], s = cT2J[p];
            float B2v[9];
            #pragma unroll
            for (int z = 0; z < 3; ++z)
                #pragma unroll
                for (int w = 0; w < 3; ++w) {
                    float acc = 0.f;
                    #pragma unroll
                    for (int x = 0; x < 3; ++x)
                        #pragma unroll
                        for (int y = 0; y < 3; ++y)
                            acc += m3[r*10 + s3c(x,y,z)] * m3[s*10 + s3c(x,y,w)];
                    B2v[z*3+w] = acc;
                }
            #pragma unroll
            for (int t = 0; t < 5; ++t) {
                float acc = 0.f;
                #pragma unroll
                for (int z = 0; z < 3; ++z)
                    #pragma unroll
                    for (int w = 0; w < 3; ++w)
                        acc += B2v[z*3+w] * m2[t*6 + s2c(z,w)];
                STF(160 + p*5 + t, acc);
            }
        }
        #pragma unroll
        for (int p = 0; p < 15; ++p) {
            int r = cT2I[p], s = cT2J[p];
            float o[9];
            #pragma unroll
            for (int x = 0; x < 3; ++x)
                #pragma unroll
                for (int y = 0; y < 3; ++y) o[x*3+y] = m1[r*3+x] * m1[s*3+y];
            #pragma unroll
            for (int t = 0; t < 5; ++t) {
                float v = 0.f;
                #pragma unroll
                for (int x = 0; x < 3; ++x)
                    #pragma unroll
                    for (int y = 0; y < 3; ++y)
                        v += o[x*3+y] * m2[t*6 + s2c(x,y)];
                STF(85 + p*5 + t, v);
            }
        }
    } else {
        float m1[15], m2[30], m3[50];
        #pragma unroll
        for (int e = 0; e < 15; ++e) m1[e] = LDM(5 + e);
        #pragma unroll
        for (int e = 0; e < 30; ++e) m2[e] = LDM(20 + e);
        #pragma unroll
        for (int e = 0; e < 50; ++e) m3[e] = LDM(50 + e);
        #pragma unroll
        for (int p = 0; p < 15; ++p) {
            int r = cT2I[p], s = cT2J[p];
            float v = 0.f;
            #pragma unroll
            for (int k = 0; k < 10; ++k) v += cW3[k] * m3[r*10+k] * m3[s*10+k];
            STF(35 + p, v);
        }
        #pragma unroll
        for (int r = 0; r < 5; ++r)
            #pragma unroll
            for (int s = 0; s < 5; ++s) {
                float A3z[3];
                #pragma unroll
                for (int z = 0; z < 3; ++z) {
                    float v = 0.f;
                    #pragma unroll
                    for (int x = 0; x < 3; ++x)
                        #pragma unroll
                        for (int y = 0; y < 3; ++y)
                            v += m3[r*10 + s3c(x,y,z)] * m2[s*6 + s2c(x,y)];
                    A3z[z] = v;
                }
                #pragma unroll
                for (int t = 0; t < 5; ++t) {
                    float v = A3z[0]*m1[t*3] + A3z[1]*m1[t*3+1] + A3z[2]*m1[t*3+2];
                    STF(235 + r*25 + s*5 + t, v);
                }
            }
    }
    __syncthreads();

    // coalesced copy-out: wave wv handles rows wv*16 .. wv*16+15
    __hip_bfloat16* dst = feats + (size_t)blockIdx.x * 64 * KP1;
    #pragma unroll
    for (int rr = 0; rr < 16; ++rr) {
        int row = wv * 16 + rr;
        #pragma unroll
        for (int it = 0; it < 3; ++it) {
            uint32_t v = *(const uint32_t*)&ldsF[row][(it*64 + lane)*2];
            *(uint32_t*)&dst[(size_t)row * KP1 + (size_t)(it*64 + lane)*2] = v;
        }
    }
    #undef LDM
    #undef STF
}

// ---------- bf16 MFMA GEMM, 64x128 tile, BK=32, 3-buffer counted-vmcnt pipeline ----------
// Round-11 occupancy win kept (64x128, ~1280 blocks); adds:
//  (1) T3/T4: prefetch 2 K-tiles ahead; per-iter s_waitcnt vmcnt(3) (oldest-first,
//      m135) + raw s_barrier + sched_barrier(0) -- no full drain in steady state.
//  (2) fuse=0 epilogue: stage 64x128 bf16 output in LDS (reuse Bs), then write C
//      as 256B-contiguous row runs (vs 32B MFMA-fragment scatter).
// LDS 36KB -> 4 blocks/CU. LDS dest linear; XOR swizzle on GLOBAL source chunk.
__global__ __launch_bounds__(256) void gemm_mfma_swish(
    const __hip_bfloat16* __restrict__ A, const __hip_bfloat16* __restrict__ Bt,
    const float* __restrict__ bias, __hip_bfloat16* __restrict__ C,
    const float* __restrict__ w3, float* __restrict__ outacc,
    const int* __restrict__ Zmask,
    int Kp, int M, int Mtiles, float alpha, float a3, int fuse)
{
    __shared__ float4 As[3][256];   // 64 rows x 4 chunks x 3 buffers = 12 KB
    __shared__ float4 Bs[3][512];   // 128 rows x 4 chunks x 3 buffers = 24 KB
    int tid = threadIdx.x;
    int wave = tid >> 6, lane = tid & 63;
    int quad = lane >> 4, l16 = lane & 15;
    int wm = wave >> 1, wn = wave & 1;   // 2x2 waves: 32-row x 64-col each
    int bid = blockIdx.x;
    int mt = (bid >> 5) * 8 + (bid & 7);
    int nt = (bid >> 3) & 3;
    if (mt >= Mtiles) return;
    int rowBase = mt * 64;
    int colBase = nt * 128;

    floatx4 acc[2][4] = {};

    int rA = tid >> 2, cA = (tid & 3) ^ ((rA >> 1) & 3);
    int rB0 = tid >> 2, cB0 = cA;
    int rB1 = rB0 + 64, cB1 = (tid & 3) ^ ((rB1 >> 1) & 3);

    const char* gA  = (const char*)A  + ((size_t)(rowBase + rA)  * Kp) * 2 + cA  * 16;
    const char* gB0 = (const char*)Bt + ((size_t)(colBase + rB0) * Kp) * 2 + cB0 * 16;
    const char* gB1 = (const char*)Bt + ((size_t)(colBase + rB1) * Kp) * 2 + cB1 * 16;

    char* lA = (char*)As;
    char* lB = (char*)Bs;
    int wvoff = wave << 10;          // wave-uniform LDS base offset (64 lanes x 16B)

    int posA[2], posB[4];
    #pragma unroll
    for (int t = 0; t < 2; ++t) {
        int rr = wm * 32 + t * 16 + l16;
        posA[t] = rr * 4 + (quad ^ ((rr >> 1) & 3));
    }
    #pragma unroll
    for (int u = 0; u < 4; ++u) {
        int cc = wn * 64 + u * 16 + l16;
        posB[u] = cc * 4 + (quad ^ ((cc >> 1) & 3));
    }

    int nK = Kp >> 5;

    // stage K-tile kt into buffer b: A 1 gload, B 2 gloads per thread (3 total)
    #define STAGE(b, kt) { int go_ = (kt) << 6;                                  \
        gload_lds16(gA  + go_, lA + ((b) << 12) + wvoff);                        \
        gload_lds16(gB0 + go_, lB + ((b) << 13) + wvoff);                        \
        gload_lds16(gB1 + go_, lB + ((b) << 13) + 4096 + wvoff); }

    // prologue: tiles 0 and 1 in flight (nK >= 12 always)
    STAGE(0, 0);
    STAGE(1, 1);

    for (int kt = 0; kt < nK; ++kt) {
        int b = kt % 3;
        // wait for tile kt's 3 loads (oldest); keep tile kt+1's 3 in flight
        if (kt + 1 < nK) asm volatile("s_waitcnt vmcnt(3)" ::: "memory");
        else             asm volatile("s_waitcnt vmcnt(0)" ::: "memory");
        __builtin_amdgcn_s_barrier();
        __builtin_amdgcn_sched_barrier(0);
        if (kt + 2 < nK) { int b2 = (kt + 2) % 3; STAGE(b2, kt + 2); }
        short8 af[2], bf[4];
        #pragma unroll
        for (int t = 0; t < 2; ++t) af[t] = *(const short8*)(As[b] + posA[t]);
        #pragma unroll
        for (int u = 0; u < 4; ++u) bf[u] = *(const short8*)(Bs[b] + posB[u]);
        #pragma unroll
        for (int t = 0; t < 2; ++t)
            #pragma unroll
            for (int u = 0; u < 4; ++u)
                acc[t][u] = __builtin_amdgcn_mfma_f32_16x16x32_bf16(
                    af[t], bf[u], acc[t][u], 0, 0, 0);
    }
    #undef STAGE

    if (!fuse) {
        // stage output tile in LDS (reuse Bs: 24KB >= 16KB), then coalesced store
        __syncthreads();
        __hip_bfloat16* lc = (__hip_bfloat16*)Bs;   // [64][128]
        #pragma unroll
        for (int u = 0; u < 4; ++u) {
            int lcol = wn * 64 + u * 16 + l16;
            float bc = 0.1f * bias[colBase + lcol];
            #pragma unroll
            for (int t = 0; t < 2; ++t) {
                int lrow0 = wm * 32 + t * 16 + quad * 4;
                #pragma unroll
                for (int r = 0; r < 4; ++r) {
                    float x = alpha * acc[t][u][r] + bc;
                    float v = x / (1.f + expf(-x));
                    lc[(lrow0 + r) * 128 + lcol] = __float2bfloat16(v);
                }
            }
        }
        __syncthreads();
        // 4 passes x (16 rows x 16 segs x 16B): 256B-contiguous per row
        #pragma unroll
        for (int ps = 0; ps < 4; ++ps) {
            int row = ps * 16 + (tid >> 4);
            int seg = tid & 15;
            float4 v4 = *(const float4*)&lc[row * 128 + seg * 8];
            *(float4*)&C[(size_t)(rowBase + row) * UNITS + colBase + seg * 8] = v4;
        }
    } else {
        float rowsum[2][4] = {};
        #pragma unroll
        for (int u = 0; u < 4; ++u) {
            int col = colBase + wn * 64 + u * 16 + l16;
            float bc = 0.1f * bias[col];
            float w3c = w3[col] * a3;
            #pragma unroll
            for (int t = 0; t < 2; ++t)
                #pragma unroll
                for (int r = 0; r < 4; ++r) {
                    float x = alpha * acc[t][u][r] + bc;
                    float v = x / (1.f + expf(-x));
                    rowsum[t][r] += v * w3c;
                }
        }
        #pragma unroll
        for (int t = 0; t < 2; ++t)
            #pragma unroll
            for (int r = 0; r < 4; ++r) {
                float s = rowsum[t][r];
                s += __shfl_xor(s, 1, 64);
                s += __shfl_xor(s, 2, 64);
                s += __shfl_xor(s, 4, 64);
                s += __shfl_xor(s, 8, 64);
                rowsum[t][r] = s;
            }
        if (l16 == 0) {
            #pragma unroll
            for (int t = 0; t < 2; ++t) {
                int row0 = rowBase + wm * 32 + t * 16 + quad * 4;
                #pragma unroll
                for (int r = 0; r < 4; ++r) {
                    int row = row0 + r;
                    if (row < M && Zmask[row] > 0)
                        atomicAdd(&outacc[row], rowsum[t][r]);
                }
            }
        }
    }
}

static inline size_t align_up(size_t x, size_t a) { return (x + a - 1) & ~(a - 1); }

extern "C" void kernel_launch(void* const* d_in, const int* in_sizes, int n_in,
                              void* d_out, int out_size, void* d_ws, size_t ws_size,
                              hipStream_t stream)
{
    const float* R       = (const float*)d_in[0];
    const int*   Z       = (const int*)  d_in[1];
    const int*   nbr     = (const int*)  d_in[2];
    const float* offsets = (const float*)d_in[4];
    const float* emb     = (const float*)d_in[5];
    const float* W1      = (const float*)d_in[6];
    const float* b1      = (const float*)d_in[7];
    const float* W2      = (const float*)d_in[8];
    const float* b2      = (const float*)d_in[9];
    const float* W3      = (const float*)d_in[10];
    const float* b3      = (const float*)d_in[11];

    int natoms = in_sizes[0] / 3;
    int npairs = in_sizes[2] / 2;
    int Mpad = ((natoms + 127) / 128) * 128;
    int Mtiles = Mpad / 64;

    char* ws = (char*)d_ws;
    size_t off = 0;
    int* counts = (int*)(ws + off); off = align_up(off + natoms*4, 256);
    float* tmpRec = (float*)(ws + off); off = align_up(off + (size_t)natoms*CAP*8*4, 256);
    float* momG = (float*)(ws + off); off = align_up(off + (size_t)Mpad*100*4, 256);
    __hip_bfloat16* W1t   = (__hip_bfloat16*)(ws + off); off = align_up(off + (size_t)UNITS*KP1*2, 256);
    __hip_bfloat16* W2t   = (__hip_bfloat16*)(ws + off); off = align_up(off + (size_t)UNITS*UNITS*2, 256);
    __hip_bfloat16* feats = (__hip_bfloat16*)(ws + off); off = align_up(off + (size_t)Mpad*KP1*2, 256);
    __hip_bfloat16* h1    = (__hip_bfloat16*)(ws + off); off = align_up(off + (size_t)Mpad*UNITS*2, 256);

    // host-side double-precision basis constants (exact vs numpy reference)
    BasisConsts bc;
    {
        const double betta = 49.0 / 36.0;
        const double delta = 5.5 / 6.0;
        const double log2e = 1.4426950408889634073599246810;
        bc.f0k = (float)(-betta * log2e);
        bc.kg  = (float)(2.0 * betta * delta * log2e);
        for (int b = 0; b < 6; ++b)
            bc.c[b] = (float)exp(-betta * delta * (1.0 + delta * (2*b + 1)));
        bc.scale = (float)(pow(2.0 * betta / M_PI, 0.75) / sqrt(7.0));
    }

    hipMemsetAsync(counts, 0, (size_t)natoms * sizeof(int), stream);

    int pgrid = (npairs + 255) / 256;
    int totalBlocks = pgrid + 448 + (natoms + 255) / 256;
    pair_prep_kernel<<<dim3(totalBlocks), 256, 0, stream>>>(
        R, Z, nbr, offsets, emb, counts, tmpRec, npairs, bc,
        W1, W2, W1t, W2t, (float*)d_out, b3, pgrid, natoms);

    moment_kernel<<<dim3(Mpad / 4), 256, 0, stream>>>(
        tmpRec, counts, momG, natoms);
    feat_kernel<<<dim3(Mpad / 64), 256, 0, stream>>>(momG, feats);

    float a1 = 1.0f / sqrtf((float)NFEAT);
    float a2 = 1.0f / sqrtf((float)UNITS);
    int gemmGrid = ((Mtiles + 7) / 8) * 8 * 4;
    gemm_mfma_swish<<<dim3(gemmGrid), 256, 0, stream>>>(
        feats, W1t, b1, h1, nullptr, nullptr, nullptr, KP1, natoms, Mtiles, a1, 0.f, 0);
    gemm_mfma_swish<<<dim3(gemmGrid), 256, 0, stream>>>(
        h1, W2t, b2, nullptr, W3, (float*)d_out, Z, UNITS, natoms, Mtiles, a2, a2, 1);
}

// Round 14
// 186.270 us; speedup vs baseline: 1.0332x; 1.0332x over previous
//
#include <hip/hip_runtime.h>
#include <hip/hip_bf16.h>
#include <cmath>

#define NSP 119
#define UNITS 512
#define NFEAT 360
#define KP1 384          // NFEAT padded to multiple of 32
#define CAP 128          // per-atom pair-segment capacity (mean ~21, >13 sigma)

typedef __attribute__((ext_vector_type(8))) short short8;
typedef __attribute__((ext_vector_type(4))) float floatx4;

#define AS1 __attribute__((address_space(1)))
#define AS3 __attribute__((address_space(3)))

// async global->LDS, 16B per lane; lds dest = wave-uniform base + lane*16
__device__ __forceinline__ void gload_lds16(const void* g, void* l) {
    __builtin_amdgcn_global_load_lds((AS1 void*)(size_t)g, (AS3 void*)l, 16, 0, 0);
}

// compile-time symmetric-index helpers (fold under full unroll)
__device__ __host__ constexpr int s2c(int i, int j) {
    return (i > j) ? i*(i+1)/2 + j : j*(j+1)/2 + i;
}
__device__ __host__ constexpr int s3c(int x, int y, int z) {
    int A = x > y ? x : y; A = A > z ? A : z;
    int C = x < y ? x : y; C = C < z ? C : z;
    int B = x + y + z - A - C;
    return A*(A+1)*(A+2)/6 + B*(B+1)/2 + C;
}

struct BasisConsts {
    float f0k;      // -betta * log2(e)
    float kg;       // 2*betta*delta*log2(e)
    float scale;    // rad_norm / sqrt(7)
    float c[6];     // exp(-betta*delta*(1 + delta*(2b+1)))
};

// ---------- phase 1 (fused): pair records + W transposes + out init ----------
__global__ __launch_bounds__(256) void pair_prep_kernel(
    const float* __restrict__ R, const int* __restrict__ Z,
    const int* __restrict__ nbr, const float* __restrict__ offsets,
    const float* __restrict__ emb, int* __restrict__ counts,
    float* __restrict__ tmpRec, int npairs, BasisConsts bc,
    const float* __restrict__ W1, const float* __restrict__ W2,
    __hip_bfloat16* __restrict__ W1t, __hip_bfloat16* __restrict__ W2t,
    float* __restrict__ outbuf, const float* __restrict__ b3,
    int pgrid, int natoms)
{
    int blk = blockIdx.x;
    if (blk >= pgrid) {
        int b = blk - pgrid;
        if (b < 448) {
            __shared__ float tile[32][33];
            const float* W; __hip_bfloat16* Wt; int K, Kp, ik, in;
            if (b < 192) { W = W1; Wt = W1t; K = NFEAT; Kp = KP1; ik = b % 12; in = b / 12; }
            else { int b2 = b - 192; W = W2; Wt = W2t; K = UNITS; Kp = UNITS; ik = b2 & 15; in = b2 >> 4; }
            int tx = threadIdx.x & 31, ty = threadIdx.x >> 5;
            int n = in * 32 + tx;                      // N = 512 for both matrices
            #pragma unroll
            for (int pp = 0; pp < 4; ++pp) {
                int kk = ty + pp * 8;
                int k = ik * 32 + kk;
                tile[kk][tx] = (k < K) ? W[(size_t)k * UNITS + n] : 0.f;
            }
            __syncthreads();
            #pragma unroll
            for (int pp = 0; pp < 4; ++pp) {
                int nn = ty + pp * 8;
                Wt[(size_t)(in * 32 + nn) * Kp + ik * 32 + tx] = __float2bfloat16(tile[tx][nn]);
            }
        } else {
            int idx = (b - 448) * 256 + threadIdx.x;
            if (idx < natoms)
                outbuf[idx] = (Z[idx] > 0) ? 0.1f * b3[0] : 0.f;
        }
        return;
    }

    int p = blk * 256 + threadIdx.x;
    if (p >= npairs) return;
    int i = nbr[p];
    int j = nbr[npairs + p];
    float dx = R[3*j]   - R[3*i]   + offsets[3*p];
    float dy = R[3*j+1] - R[3*i+1] + offsets[3*p+1];
    float dz = R[3*j+2] - R[3*i+2] + offsets[3*p+2];
    float dr2 = fmaf(dz, dz, fmaf(dy, dy, dx*dx));
    if (dr2 >= 36.0f) return;
    int pos = atomicAdd(&counts[i], 1);
    if (pos >= CAP) return;   // statistically impossible; memory-safety guard

    float dr  = sqrtf(dr2);
    float inv = 1.0f / (dr + 1e-5f);
    float d0  = dr - 0.5f;
    float basis[7];
    basis[0] = exp2f(bc.f0k * d0 * d0);
    float G  = exp2f(bc.kg * dr);
    float cur = basis[0];
    #pragma unroll
    for (int b = 0; b < 6; ++b) { cur *= G * bc.c[b]; basis[b+1] = cur; }
    float cut = 0.5f * (__cosf(dr * 0.52359877559829887f) + 1.0f);  // pi/R_MAX
    float s = bc.scale * cut;

    const float* e = emb + ((size_t)Z[j] * NSP + Z[i]) * 35;
    float ev[35];
    __builtin_memcpy(ev, e, 35 * sizeof(float));

    float rec[8];
    #pragma unroll
    for (int r = 0; r < 5; ++r) {
        float acc = 0.f;
        #pragma unroll
        for (int b = 0; b < 7; ++b) acc += ev[r*7+b] * basis[b];
        rec[r] = s * acc;
    }
    rec[5] = dx * inv; rec[6] = dy * inv; rec[7] = dz * inv;
    float4* out = (float4*)(tmpRec + ((size_t)i * CAP + pos) * 8);
    out[0] = make_float4(rec[0], rec[1], rec[2], rec[3]);
    out[1] = make_float4(rec[4], rec[5], rec[6], rec[7]);
}

// ---------- phase 2a: one wave per atom -> 100 compressed moments to global ----------
#define SREC 28
__global__ __launch_bounds__(256) void moment_kernel(
    const float* __restrict__ tmpRec, const int* __restrict__ counts,
    float* __restrict__ momG, int natoms)
{
    int wv = threadIdx.x >> 6, lane = threadIdx.x & 63;
    int a = blockIdx.x * 4 + wv;
    __shared__ float stage[4][64][SREC];

    int cnt = 0;
    if (a < natoms) cnt = min(counts[a], CAP);   // pad atoms: zeros

    int cr0, pk0;
    if (lane < 5)       { cr0 = lane;            pk0 = 0; }
    else if (lane < 20) { int c = lane - 5;      cr0 = c / 3;  pk0 = 1 + c % 3; }
    else if (lane < 50) { int c = lane - 20;     cr0 = c / 6;  pk0 = 4 + c % 6; }
    else                { int c = lane - 50;     cr0 = c / 10; pk0 = 10 + c % 10; }
    int cr1 = 0, pk1 = 0;
    if (lane < 36) { int c = 14 + lane; cr1 = c / 10; pk1 = 10 + c % 10; }

    float acc0 = 0.f, acc1 = 0.f;
    for (int base = 0; base < cnt; base += 64) {
        int m = min(64, cnt - base);
        if (lane < m) {
            const float4* pd = (const float4*)(tmpRec + ((size_t)a * CAP + base + lane) * 8);
            float4 u = pd[0], v = pd[1];
            float x = v.y, y = v.z, z = v.w;
            float s2_0 = x*x, s2_1 = y*x, s2_2 = y*y, s2_3 = z*x, s2_4 = z*y, s2_5 = z*z;
            float* st = stage[wv][lane];
            ((float4*)st)[0] = u;                                    // rad0..3
            ((float4*)st)[1] = make_float4(v.x, 1.0f, x, y);         // rad4, p0=1, p1, p2
            ((float4*)st)[2] = make_float4(z, s2_0, s2_1, s2_2);     // p3..p6
            ((float4*)st)[3] = make_float4(s2_3, s2_4, s2_5, s2_0*x);// p7..p9, p10=xxx
            ((float4*)st)[4] = make_float4(s2_0*y, s2_2*x, s2_2*y, s2_0*z); // p11..p14
            ((float4*)st)[5] = make_float4(s2_1*z, s2_2*z, s2_5*x, s2_5*y); // p15..p18
            ((float4*)st)[6] = make_float4(s2_5*z, 0.f, 0.f, 0.f);   // p19, pad
        }
        __builtin_amdgcn_wave_barrier();
        for (int q = 0; q < m; ++q) {
            const float* s = stage[wv][q];
            acc0 += s[cr0] * s[5 + pk0];
            acc1 += s[cr1] * s[5 + pk1];
        }
        __builtin_amdgcn_wave_barrier();
    }
    size_t base = (size_t)(a >> 6) * 6400 + (size_t)(a & 63);
    momG[base + (size_t)lane * 64] = acc0;
    if (lane < 36) momG[base + (size_t)(64 + lane) * 64] = acc1;
}

// ---------- phase 2b: lane = atom, wave = feature group; all indices constexpr ----------
#define LROW 390   // LDS row stride in bf16: 195 words, 195%32=3 -> conflict-free
__global__ __launch_bounds__(256) void feat_kernel(
    const float* __restrict__ momG, __hip_bfloat16* __restrict__ feats)
{
    constexpr int cT2I[15] = {0,1,1,2,2,2,3,3,3,3,4,4,4,4,4};
    constexpr int cT2J[15] = {0,0,1,0,1,2,0,1,2,3,0,1,2,3,4};
    constexpr int cT3A[35] = {0, 1,1,1, 2,2,2,2,2,2, 3,3,3,3,3,3,3,3,3,3, 4,4,4,4,4,4,4,4,4,4,4,4,4,4,4};
    constexpr int cT3B[35] = {0, 0,1,1, 0,1,1,2,2,2, 0,1,1,2,2,2,3,3,3,3, 0,1,1,2,2,2,3,3,3,3,4,4,4,4,4};
    constexpr int cT3C[35] = {0, 0,0,1, 0,0,1,0,1,2, 0,0,1,0,1,2,0,1,2,3, 0,0,1,0,1,2,0,1,2,3,0,1,2,3,4};
    constexpr float cW2[6]  = {1.f,2.f,1.f,2.f,2.f,1.f};
    constexpr float cW3[10] = {1.f,3.f,3.f,1.f,3.f,6.f,3.f,3.f,3.f,1.f};

    __shared__ __hip_bfloat16 ldsF[64][LROW];
    int wv = threadIdx.x >> 6, lane = threadIdx.x & 63;
    const float* mg = momG + (size_t)blockIdx.x * 6400 + lane;

    #define LDM(e) mg[(e) * 64]
    #define STF(f, v) ldsF[lane][(f)] = __float2bfloat16(v)

    if (wv == 0) {
        float m3[50], m2[30];
        #pragma unroll
        for (int e = 0; e < 50; ++e) m3[e] = LDM(50 + e);
        #pragma unroll
        for (int e = 0; e < 30; ++e) m2[e] = LDM(20 + e);
        #pragma unroll
        for (int p = 0; p < 10; ++p) {
            int r = cT2I[p], s = cT2J[p];
            float B2v[9];
            #pragma unroll
            for (int z = 0; z < 3; ++z)
                #pragma unroll
                for (int w = 0; w < 3; ++w) {
                    float acc = 0.f;
                    #pragma unroll
                    for (int x = 0; x < 3; ++x)
                        #pragma unroll
                        for (int y = 0; y < 3; ++y)
                            acc += m3[r*10 + s3c(x,y,z)] * m3[s*10 + s3c(x,y,w)];
                    B2v[z*3+w] = acc;
                }
            #pragma unroll
            for (int t = 0; t < 5; ++t) {
                float acc = 0.f;
                #pragma unroll
                for (int z = 0; z < 3; ++z)
                    #pragma unroll
                    for (int w = 0; w < 3; ++w)
                        acc += B2v[z*3+w] * m2[t*6 + s2c(z,w)];
                STF(160 + p*5 + t, acc);
            }
        }
    } else if (wv == 1) {
        float m0[5], m1[15], m2[30];
        #pragma unroll
        for (int e = 0; e < 5; ++e)  m0[e] = LDM(e);
        #pragma unroll
        for (int e = 0; e < 15; ++e) m1[e] = LDM(5 + e);
        #pragma unroll
        for (int e = 0; e < 30; ++e) m2[e] = LDM(20 + e);
        #pragma unroll
        for (int r = 0; r < 5; ++r) STF(r, m0[r]);
        #pragma unroll
        for (int p = 0; p < 15; ++p) {
            int r = cT2I[p], s = cT2J[p];
            float v1 = m1[r*3]*m1[s*3] + m1[r*3+1]*m1[s*3+1] + m1[r*3+2]*m1[s*3+2];
            STF(5 + p, v1);
            float v2 = 0.f;
            #pragma unroll
            for (int k = 0; k < 6; ++k) v2 += cW2[k] * m2[r*6+k] * m2[s*6+k];
            STF(20 + p, v2);
        }
        #pragma unroll
        for (int q = 0; q < 35; ++q) {
            int r = cT3A[q], s = cT3B[q], t = cT3C[q];
            float v = 0.f;
            #pragma unroll
            for (int x = 0; x < 3; ++x)
                #pragma unroll
                for (int y = 0; y < 3; ++y) {
                    float d = 0.f;
                    #pragma unroll
                    for (int z = 0; z < 3; ++z)
                        d += m2[s*6 + s2c(x,z)] * m2[t*6 + s2c(y,z)];
                    v += m2[r*6 + s2c(x,y)] * d;
                }
            STF(50 + q, v);
        }
        #pragma unroll
        for (int f = NFEAT; f < KP1; ++f) STF(f, 0.f);
    } else if (wv == 2) {
        float m1[15], m2[30], m3[50];
        #pragma unroll
        for (int e = 0; e < 15; ++e) m1[e] = LDM(5 + e);
        #pragma unroll
        for (int e = 0; e < 30; ++e) m2[e] = LDM(20 + e);
        #pragma unroll
        for (int e = 0; e < 50; ++e) m3[e] = LDM(50 + e);
        #pragma unroll
        for (int p = 10; p < 15; ++p) {
            int r = cT2I[p], s = cT2J[p];
            float B2v[9];
            #pragma unroll
            for (int z = 0; z < 3; ++z)
                #pragma unroll
                for (int w = 0; w < 3; ++w) {
                    float acc = 0.f;
                    #pragma unroll
                    for (int x = 0; x < 3; ++x)
                        #pragma unroll
                        for (int y = 0; y < 3; ++y)
                            acc += m3[r*10 + s3c(x,y,z)] * m3[s*10 + s3c(x,y,w)];
                    B2v[z*3+w] = acc;
                }
            #pragma unroll
            for (int t = 0; t < 5; ++t) {
                float acc = 0.f;
                #pragma unroll
                for (int z = 0; z < 3; ++z)
                    #pragma unroll
                    for (int w = 0; w < 3; ++w)
                        acc += B2v[z*3+w] * m2[t*6 + s2c(z,w)];
                STF(160 + p*5 + t, acc);
            }
        }
        #pragma unroll
        for (int p = 0; p < 15; ++p) {
            int r = cT2I[p], s = cT2J[p];
            float o[9];
            #pragma unroll
            for (int x = 0; x < 3; ++x)
                #pragma unroll
                for (int y = 0; y < 3; ++y) o[x*3+y] = m1[r*3+x] * m1[s*3+y];
            #pragma unroll
            for (int t = 0; t < 5; ++t) {
                float v = 0.f;
                #pragma unroll
                for (int x = 0; x < 3; ++x)
                    #pragma unroll
                    for (int y = 0; y < 3; ++y)
                        v += o[x*3+y] * m2[t*6 + s2c(x,y)];
                STF(85 + p*5 + t, v);
            }
        }
    } else {
        float m1[15], m2[30], m3[50];
        #pragma unroll
        for (int e = 0; e < 15; ++e) m1[e] = LDM(5 + e);
        #pragma unroll
        for (int e = 0; e < 30; ++e) m2[e] = LDM(20 + e);
        #pragma unroll
        for (int e = 0; e < 50; ++e) m3[e] = LDM(50 + e);
        #pragma unroll
        for (int p = 0; p < 15; ++p) {
            int r = cT2I[p], s = cT2J[p];
            float v = 0.f;
            #pragma unroll
            for (int k = 0; k < 10; ++k) v += cW3[k] * m3[r*10+k] * m3[s*10+k];
            STF(35 + p, v);
        }
        #pragma unroll
        for (int r = 0; r < 5; ++r)
            #pragma unroll
            for (int s = 0; s < 5; ++s) {
                float A3z[3];
                #pragma unroll
                for (int z = 0; z < 3; ++z) {
                    float v = 0.f;
                    #pragma unroll
                    for (int x = 0; x < 3; ++x)
                        #pragma unroll
                        for (int y = 0; y < 3; ++y)
                            v += m3[r*10 + s3c(x,y,z)] * m2[s*6 + s2c(x,y)];
                    A3z[z] = v;
                }
                #pragma unroll
                for (int t = 0; t < 5; ++t) {
                    float v = A3z[0]*m1[t*3] + A3z[1]*m1[t*3+1] + A3z[2]*m1[t*3+2];
                    STF(235 + r*25 + s*5 + t, v);
                }
            }
    }
    __syncthreads();

    // coalesced copy-out: wave wv handles rows wv*16 .. wv*16+15
    __hip_bfloat16* dst = feats + (size_t)blockIdx.x * 64 * KP1;
    #pragma unroll
    for (int rr = 0; rr < 16; ++rr) {
        int row = wv * 16 + rr;
        #pragma unroll
        for (int it = 0; it < 3; ++it) {
            uint32_t v = *(const uint32_t*)&ldsF[row][(it*64 + lane)*2];
            *(uint32_t*)&dst[(size_t)row * KP1 + (size_t)(it*64 + lane)*2] = v;
        }
    }
    #undef LDM
    #undef STF
}

// ---------- bf16 MFMA GEMM, 64x128 tile, BK=32, global_load_lds double-buffer ----------
// Round-11 winner (simple drain schedule; counted-vmcnt variants measured neutral
// or worse on this short-K shape). Single change vs round 11: fuse=0 epilogue
// stages the 64x128 bf16 output tile in LDS (reuses Bs, exactly 16 KB) and
// stores C as 256B-contiguous row runs instead of 32B MFMA-fragment scatter.
// Grid swizzle: mt = (bid>>5)*8 + (bid&7), nt = (bid>>3)&3 (XCD-grouped).
__global__ __launch_bounds__(256) void gemm_mfma_swish(
    const __hip_bfloat16* __restrict__ A, const __hip_bfloat16* __restrict__ Bt,
    const float* __restrict__ bias, __hip_bfloat16* __restrict__ C,
    const float* __restrict__ w3, float* __restrict__ outacc,
    const int* __restrict__ Zmask,
    int Kp, int M, int Mtiles, float alpha, float a3, int fuse)
{
    __shared__ float4 As[2][256];   // 64 rows x 4 chunks x 2 buffers = 8 KB
    __shared__ float4 Bs[2][512];   // 128 rows x 4 chunks x 2 buffers = 16 KB
    int tid = threadIdx.x;
    int wave = tid >> 6, lane = tid & 63;
    int quad = lane >> 4, l16 = lane & 15;
    int wm = wave >> 1, wn = wave & 1;   // 2x2 waves: 32-row x 64-col each
    int bid = blockIdx.x;
    int mt = (bid >> 5) * 8 + (bid & 7);
    int nt = (bid >> 3) & 3;
    if (mt >= Mtiles) return;
    int rowBase = mt * 64;
    int colBase = nt * 128;

    floatx4 acc[2][4] = {};

    int rA = tid >> 2, cA = (tid & 3) ^ ((rA >> 1) & 3);
    int rB0 = tid >> 2, cB0 = cA;                 // same pattern rows 0..63
    int rB1 = rB0 + 64, cB1 = (tid & 3) ^ ((rB1 >> 1) & 3);

    const char* gA  = (const char*)A  + ((size_t)(rowBase + rA)  * Kp) * 2 + cA  * 16;
    const char* gB0 = (const char*)Bt + ((size_t)(colBase + rB0) * Kp) * 2 + cB0 * 16;
    const char* gB1 = (const char*)Bt + ((size_t)(colBase + rB1) * Kp) * 2 + cB1 * 16;

    char* lA = (char*)As;
    char* lB = (char*)Bs;
    int wvoff = wave << 10;          // wave-uniform LDS base offset (64 lanes x 16B)

    int posA[2], posB[4];
    #pragma unroll
    for (int t = 0; t < 2; ++t) {
        int rr = wm * 32 + t * 16 + l16;
        posA[t] = rr * 4 + (quad ^ ((rr >> 1) & 3));
    }
    #pragma unroll
    for (int u = 0; u < 4; ++u) {
        int cc = wn * 64 + u * 16 + l16;
        posB[u] = cc * 4 + (quad ^ ((cc >> 1) & 3));
    }

    int nK = Kp >> 5;

    // stage K-tile kt into buffer b: A 1 gload, B 2 gloads per thread
    #define STAGE(b, kt) { int go_ = (kt) << 6;                                  \
        gload_lds16(gA  + go_, lA + ((b) << 12) + wvoff);                        \
        gload_lds16(gB0 + go_, lB + ((b) << 13) + wvoff);                        \
        gload_lds16(gB1 + go_, lB + ((b) << 13) + 4096 + wvoff); }

    STAGE(0, 0);
    __syncthreads();

    for (int kt = 0; kt < nK; ++kt) {
        int buf = kt & 1;
        if (kt + 1 < nK) STAGE(buf ^ 1, kt + 1);
        short8 af[2], bf[4];
        #pragma unroll
        for (int t = 0; t < 2; ++t) af[t] = *(const short8*)(As[buf] + posA[t]);
        #pragma unroll
        for (int u = 0; u < 4; ++u) bf[u] = *(const short8*)(Bs[buf] + posB[u]);
        #pragma unroll
        for (int t = 0; t < 2; ++t)
            #pragma unroll
            for (int u = 0; u < 4; ++u)
                acc[t][u] = __builtin_amdgcn_mfma_f32_16x16x32_bf16(
                    af[t], bf[u], acc[t][u], 0, 0, 0);
        // barrier: (a) all lanes done reading buf (overwritten next iter),
        // (b) drains vmcnt so the staged buf^1 is complete before next read.
        __syncthreads();
    }
    #undef STAGE

    if (!fuse) {
        // stage output tile in LDS (reuse Bs: 16 KB, exact fit), coalesced store.
        // Loop's final __syncthreads guarantees all LDS reads of Bs are done.
        __hip_bfloat16* lc = (__hip_bfloat16*)Bs;   // [64][128]
        #pragma unroll
        for (int u = 0; u < 4; ++u) {
            int lcol = wn * 64 + u * 16 + l16;
            float bc = 0.1f * bias[colBase + lcol];
            #pragma unroll
            for (int t = 0; t < 2; ++t) {
                int lrow0 = wm * 32 + t * 16 + quad * 4;
                #pragma unroll
                for (int r = 0; r < 4; ++r) {
                    float x = alpha * acc[t][u][r] + bc;
                    float v = x / (1.f + expf(-x));
                    lc[(lrow0 + r) * 128 + lcol] = __float2bfloat16(v);
                }
            }
        }
        __syncthreads();
        // 4 passes x (16 rows x 16 segs x 16B): 256B-contiguous per row
        #pragma unroll
        for (int ps = 0; ps < 4; ++ps) {
            int row = ps * 16 + (tid >> 4);
            int seg = tid & 15;
            float4 v4 = *(const float4*)&lc[row * 128 + seg * 8];
            *(float4*)&C[(size_t)(rowBase + row) * UNITS + colBase + seg * 8] = v4;
        }
    } else {
        float rowsum[2][4] = {};
        #pragma unroll
        for (int u = 0; u < 4; ++u) {
            int col = colBase + wn * 64 + u * 16 + l16;
            float bc = 0.1f * bias[col];
            float w3c = w3[col] * a3;
            #pragma unroll
            for (int t = 0; t < 2; ++t)
                #pragma unroll
                for (int r = 0; r < 4; ++r) {
                    float x = alpha * acc[t][u][r] + bc;
                    float v = x / (1.f + expf(-x));
                    rowsum[t][r] += v * w3c;
                }
        }
        #pragma unroll
        for (int t = 0; t < 2; ++t)
            #pragma unroll
            for (int r = 0; r < 4; ++r) {
                float s = rowsum[t][r];
                s += __shfl_xor(s, 1, 64);
                s += __shfl_xor(s, 2, 64);
                s += __shfl_xor(s, 4, 64);
                s += __shfl_xor(s, 8, 64);
                rowsum[t][r] = s;
            }
        if (l16 == 0) {
            #pragma unroll
            for (int t = 0; t < 2; ++t) {
                int row0 = rowBase + wm * 32 + t * 16 + quad * 4;
                #pragma unroll
                for (int r = 0; r < 4; ++r) {
                    int row = row0 + r;
                    if (row < M && Zmask[row] > 0)
                        atomicAdd(&outacc[row], rowsum[t][r]);
                }
            }
        }
    }
}

static inline size_t align_up(size_t x, size_t a) { return (x + a - 1) & ~(a - 1); }

extern "C" void kernel_launch(void* const* d_in, const int* in_sizes, int n_in,
                              void* d_out, int out_size, void* d_ws, size_t ws_size,
                              hipStream_t stream)
{
    const float* R       = (const float*)d_in[0];
    const int*   Z       = (const int*)  d_in[1];
    const int*   nbr     = (const int*)  d_in[2];
    const float* offsets = (const float*)d_in[4];
    const float* emb     = (const float*)d_in[5];
    const float* W1      = (const float*)d_in[6];
    const float* b1      = (const float*)d_in[7];
    const float* W2      = (const float*)d_in[8];
    const float* b2      = (const float*)d_in[9];
    const float* W3      = (const float*)d_in[10];
    const float* b3      = (const float*)d_in[11];

    int natoms = in_sizes[0] / 3;
    int npairs = in_sizes[2] / 2;
    int Mpad = ((natoms + 127) / 128) * 128;
    int Mtiles = Mpad / 64;

    char* ws = (char*)d_ws;
    size_t off = 0;
    int* counts = (int*)(ws + off); off = align_up(off + natoms*4, 256);
    float* tmpRec = (float*)(ws + off); off = align_up(off + (size_t)natoms*CAP*8*4, 256);
    float* momG = (float*)(ws + off); off = align_up(off + (size_t)Mpad*100*4, 256);
    __hip_bfloat16* W1t   = (__hip_bfloat16*)(ws + off); off = align_up(off + (size_t)UNITS*KP1*2, 256);
    __hip_bfloat16* W2t   = (__hip_bfloat16*)(ws + off); off = align_up(off + (size_t)UNITS*UNITS*2, 256);
    __hip_bfloat16* feats = (__hip_bfloat16*)(ws + off); off = align_up(off + (size_t)Mpad*KP1*2, 256);
    __hip_bfloat16* h1    = (__hip_bfloat16*)(ws + off); off = align_up(off + (size_t)Mpad*UNITS*2, 256);

    // host-side double-precision basis constants (exact vs numpy reference)
    BasisConsts bc;
    {
        const double betta = 49.0 / 36.0;
        const double delta = 5.5 / 6.0;
        const double log2e = 1.4426950408889634073599246810;
        bc.f0k = (float)(-betta * log2e);
        bc.kg  = (float)(2.0 * betta * delta * log2e);
        for (int b = 0; b < 6; ++b)
            bc.c[b] = (float)exp(-betta * delta * (1.0 + delta * (2*b + 1)));
        bc.scale = (float)(pow(2.0 * betta / M_PI, 0.75) / sqrt(7.0));
    }

    hipMemsetAsync(counts, 0, (size_t)natoms * sizeof(int), stream);

    int pgrid = (npairs + 255) / 256;
    int totalBlocks = pgrid + 448 + (natoms + 255) / 256;
    pair_prep_kernel<<<dim3(totalBlocks), 256, 0, stream>>>(
        R, Z, nbr, offsets, emb, counts, tmpRec, npairs, bc,
        W1, W2, W1t, W2t, (float*)d_out, b3, pgrid, natoms);

    moment_kernel<<<dim3(Mpad / 4), 256, 0, stream>>>(
        tmpRec, counts, momG, natoms);
    feat_kernel<<<dim3(Mpad / 64), 256, 0, stream>>>(momG, feats);

    float a1 = 1.0f / sqrtf((float)NFEAT);
    float a2 = 1.0f / sqrtf((float)UNITS);
    int gemmGrid = ((Mtiles + 7) / 8) * 8 * 4;
    gemm_mfma_swish<<<dim3(gemmGrid), 256, 0, stream>>>(
        feats, W1t, b1, h1, nullptr, nullptr, nullptr, KP1, natoms, Mtiles, a1, 0.f, 0);
    gemm_mfma_swish<<<dim3(gemmGrid), 256, 0, stream>>>(
        h1, W2t, b2, nullptr, W3, (float*)d_out, Z, UNITS, natoms, Mtiles, a2, a2, 1);
}